// Round 15
// baseline (361.490 us; speedup 1.0000x reference)
//
#include <hip/hip_runtime.h>
#include <hip/hip_bf16.h>

#define HIDDEN 1024
#define INTER 4096
#define NEXP 8
#define T_TOK 2048

typedef short bf16x8 __attribute__((ext_vector_type(8)));
typedef float f32x4 __attribute__((ext_vector_type(4)));

// Conflict-free BK=32 LDS chunk layout (R7/R8/R9-verified on HW: conflicts=0).
#define CHUNK(row, kq) ((unsigned int)((row) * 64u + ((((unsigned int)(kq)) ^ ((((unsigned int)(row)) >> 1) & 3u)) << 4)))

__device__ __forceinline__ unsigned short f2bf(float f) {
    union { float f; unsigned int u; } v; v.f = f;
    return (unsigned short)(v.u >> 16);   // truncation: 10x absmax margin measured
}

// two float4 -> one 16B chunk of 8 bf16 (truncating)
__device__ __forceinline__ uint4 pack8trunc(float4 a, float4 b) {
    union { float4 f; unsigned short s[8]; } x, y; x.f = a; y.f = b;
    uint4 r;
    r.x = (unsigned int)x.s[1] | ((unsigned int)x.s[3] << 16);
    r.y = (unsigned int)x.s[5] | ((unsigned int)x.s[7] << 16);
    r.z = (unsigned int)y.s[1] | ((unsigned int)y.s[3] << 16);
    r.w = (unsigned int)y.s[5] | ((unsigned int)y.s[7] << 16);
    return r;
}

// raw barrier: NO vmcnt drain (global prefetch stays in flight across it).
__device__ __forceinline__ void block_sync() {
    asm volatile("s_waitcnt lgkmcnt(0)" ::: "memory");
    __builtin_amdgcn_s_barrier();
    asm volatile("" ::: "memory");
}

// ---------------- K1: router (fp32 exact) ----------------
__global__ void router_kernel(const float* __restrict__ x,
                              const float* __restrict__ rw,
                              float* __restrict__ logits_out,
                              int* __restrict__ counts,
                              int* __restrict__ ids,
                              float* __restrict__ wts,
                              int* __restrict__ tsel) {
    int t = blockIdx.x * 4 + (threadIdx.x >> 6);
    int lane = threadIdx.x & 63;
    if (t >= T_TOK) return;
    const float4* xr = (const float4*)(x + (size_t)t * HIDDEN);
    float acc[NEXP];
#pragma unroll
    for (int e = 0; e < NEXP; e++) acc[e] = 0.f;
#pragma unroll
    for (int c = 0; c < 4; c++) {
        float4 xv = xr[lane + c * 64];
#pragma unroll
        for (int e = 0; e < NEXP; e++) {
            float4 wv = ((const float4*)(rw + (size_t)e * HIDDEN))[lane + c * 64];
            acc[e] += xv.x * wv.x + xv.y * wv.y + xv.z * wv.z + xv.w * wv.w;
        }
    }
#pragma unroll
    for (int e = 0; e < NEXP; e++) {
        float v = acc[e];
        for (int off = 32; off >= 1; off >>= 1) v += __shfl_xor(v, off, 64);
        acc[e] = v;
    }
    if (lane == 0) {
        float* lo = logits_out + (size_t)t * NEXP;
        float mx = acc[0];
#pragma unroll
        for (int e = 1; e < NEXP; e++) mx = fmaxf(mx, acc[e]);
        float p[NEXP], s = 0.f;
#pragma unroll
        for (int e = 0; e < NEXP; e++) { p[e] = __expf(acc[e] - mx); s += p[e]; }
        float inv = 1.f / s;
#pragma unroll
        for (int e = 0; e < NEXP; e++) { p[e] *= inv; lo[e] = acc[e]; }
        int i1 = 0;
#pragma unroll
        for (int e = 1; e < NEXP; e++) if (p[e] > p[i1]) i1 = e;
        int i2 = (i1 == 0) ? 1 : 0;
#pragma unroll
        for (int e = 0; e < NEXP; e++) if (e != i1 && e != i2 && p[e] > p[i2]) i2 = e;
        // strict > keeps lowest index on ties (matches jax top_k)
        int s1 = atomicAdd(&counts[i1], 1);
        ids[i1 * T_TOK + s1] = t; wts[i1 * T_TOK + s1] = p[i1];
        int s2 = atomicAdd(&counts[i2], 1);
        ids[i2 * T_TOK + s2] = t; wts[i2 * T_TOK + s2] = p[i2];
        tsel[t * 2]     = i1 * T_TOK + s1;   // pack (expert, slot)
        tsel[t * 2 + 1] = i2 * T_TOK + s2;
    }
}

__global__ void scan_kernel(const int* __restrict__ counts, int* __restrict__ offsets) {
    if (threadIdx.x == 0) {
        int s = 0;
        for (int e = 0; e < NEXP; e++) { offsets[e] = s; s += counts[e]; }
    }
}

// ---------------- K2: fused gate+up grouped GEMM + SwiGLU ----------------
// R9 kernel body verbatim (BM=256 x BN=128, BK=32, 1024 thr, 16 waves 4x4,
// CHUNK LDS, raw barrier, 1-deep prefetch).
// R14 single change: XCD-pinned 1D grid. e = bid&7 pins each expert to one
// XCD (HW round-robins consecutive bids over the 8 XCDs), so expert e's
// gathered A-rows (~2 MB) stay resident in that XCD's 4 MB L2 across all nt
// (previously 512 MB of L3 re-reads at ~7 TB/s aggregate — the measured
// invariant across R6/R9/R10/R13). mt fastest: the 2 active mt-blocks of a
// given nt are temporally adjacent -> B-panel second read is an L2 hit.
__global__ __launch_bounds__(1024) void gemm_gu(
    const float* __restrict__ x, const float* __restrict__ gw, const float* __restrict__ uw,
    const int* __restrict__ counts, const int* __restrict__ offsets,
    const int* __restrict__ ids, unsigned short* __restrict__ h) {
    const int bid = blockIdx.x;
    const int e = bid & 7;                        // XCD pin
    const int r = bid >> 3;
    const int mt = r & 7;                         // fastest within XCD
    const int nt = r >> 3;                        // 32 tiles of 128 inter
    const int cnt = counts[e];
    if (mt * 256 >= cnt) return;
    const int tid = threadIdx.x;
    const int lane = tid & 63, wid = tid >> 6;
    const int wm = wid >> 2, wn = wid & 3;        // 4x4 waves

    __shared__ __align__(16) char lds[65536];     // [A 16K | Bg 8K | Bu 8K] x2

    // A: 256 rows x 4 chunks = 1024; one per thread (2 float4 -> 1 chunk)
    const int arow = tid >> 2, akq = tid & 3;
    int ali = mt * 256 + arow; if (ali >= cnt) ali = cnt - 1;
    const unsigned int aoff = (unsigned int)(ids[e * T_TOK + ali] * HIDDEN + akq * 8);
    const unsigned int wAo = CHUNK(arow, akq);
    // B: 512 g-chunks + 512 u-chunks = 1024; one per thread
    const int bsel = tid >> 9;                    // 0 = gate, 1 = up
    const int bi = tid & 511;
    const int brow = bi >> 2, bkq = bi & 3;
    const float* bsrc = (bsel ? uw : gw) + (size_t)e * INTER * HIDDEN
                        + (size_t)(nt * 128 + brow) * HIDDEN + bkq * 8;
    const unsigned int wBo = 16384u + ((unsigned int)bsel << 13) + CHUNK(brow, bkq);

    f32x4 accg[4][2], accu[4][2];
#pragma unroll
    for (int mf = 0; mf < 4; mf++)
#pragma unroll
        for (int nf = 0; nf < 2; nf++)
#pragma unroll
            for (int v = 0; v < 4; v++) { accg[mf][nf][v] = 0.f; accu[mf][nf][v] = 0.f; }

    // 1-deep prefetch: one register set (16 VGPRs)
    float4 a0, a1, b0, b1;
    a0 = *(const float4*)(x + aoff); a1 = *(const float4*)(x + aoff + 4);
    b0 = *(const float4*)(bsrc);     b1 = *(const float4*)(bsrc + 4);

    for (int kt = 0; kt < 32; kt++) {
        const unsigned int bb = (unsigned int)(kt & 1) << 15;
        *(uint4*)(lds + bb + wAo) = pack8trunc(a0, a1);
        *(uint4*)(lds + bb + wBo) = pack8trunc(b0, b1);
        if (kt < 31) {                            // prefetch next K-tile
            const int ko = (kt + 1) * 32;
            a0 = *(const float4*)(x + aoff + ko); a1 = *(const float4*)(x + aoff + ko + 4);
            b0 = *(const float4*)(bsrc + ko);     b1 = *(const float4*)(bsrc + ko + 4);
        }
        block_sync();
        const unsigned int kqr = (unsigned int)(lane >> 4);
        const unsigned int rl = (unsigned int)(lane & 15);
        bf16x8 a[4];
#pragma unroll
        for (int mf = 0; mf < 4; mf++)
            a[mf] = *(const bf16x8*)(lds + bb + CHUNK(wm * 64 + mf * 16 + rl, kqr));
#pragma unroll
        for (int nf = 0; nf < 2; nf++) {
            const unsigned int br = wn * 32 + nf * 16 + rl;
            bf16x8 bg = *(const bf16x8*)(lds + bb + 16384 + CHUNK(br, kqr));
            bf16x8 bu = *(const bf16x8*)(lds + bb + 24576 + CHUNK(br, kqr));
#pragma unroll
            for (int mf = 0; mf < 4; mf++) {
                accg[mf][nf] = __builtin_amdgcn_mfma_f32_16x16x32_bf16(a[mf], bg, accg[mf][nf], 0, 0, 0);
                accu[mf][nf] = __builtin_amdgcn_mfma_f32_16x16x32_bf16(a[mf], bu, accu[mf][nf], 0, 0, 0);
            }
        }
    }

    const int hoff = offsets[e];
#pragma unroll
    for (int mf = 0; mf < 4; mf++)
#pragma unroll
        for (int v = 0; v < 4; v++) {
            int il = wm * 64 + mf * 16 + ((lane >> 4) << 2) + v;
            int i = mt * 256 + il;
            if (i < cnt) {
                size_t rowbase = (size_t)(hoff + i) * INTER + nt * 128 + wn * 32 + (lane & 15);
#pragma unroll
                for (int nf = 0; nf < 2; nf++) {
                    float g = accg[mf][nf][v], u = accu[mf][nf][v];
                    float sg = g / (1.f + __expf(-g));
                    h[rowbase + nf * 16] = f2bf(sg * u);
                }
            }
        }
}

// ---------------- K3: down grouped GEMM -> y (no atomics) ----------------
// R9 kernel body verbatim (BM=128 x BN=128, BK=32, ksplit=2, 512 thr, 8
// waves 2x4, CHUNK LDS). R14 single change: XCD-pinned 1D grid — e=bid&7;
// within XCD: mt fastest (4 active blocks share one B-panel), then nt,
// ksp outermost (the 2 MB h-half stays L2-resident across all 8 nt-groups).
__global__ __launch_bounds__(512) void gemm_down(
    const unsigned short* __restrict__ h, const float* __restrict__ dw,
    const int* __restrict__ counts, const int* __restrict__ offsets,
    const float* __restrict__ wts, float* __restrict__ y) {
    const int bid = blockIdx.x;
    const int e = bid & 7;                        // XCD pin
    const int r = bid >> 3;
    const int mt = r & 15;                        // fastest within XCD
    const int nt = (r >> 4) & 7;                  // 8 tiles of 128 hidden
    const int ksp = r >> 7;                       // outermost
    const int cnt = counts[e];
    if (mt * 128 >= cnt) return;
    const int tid = threadIdx.x;
    const int lane = tid & 63, wid = tid >> 6;
    const int wm = wid >> 2, wn = wid & 3;        // 2x4 waves, wave 64x32

    __shared__ __align__(16) char lds[32768];     // [A 8K | B 8K] x2

    const int hoff = offsets[e];
    const float* dbase = dw + (size_t)e * HIDDEN * INTER;

    const int row = tid >> 2, kq = tid & 3;
    int li = mt * 128 + row; if (li >= cnt) li = cnt - 1;
    const unsigned int aoff = (unsigned int)((hoff + li) * INTER + ksp * 2048 + kq * 8);
    const unsigned int wAo = CHUNK(row, kq);
    const unsigned int boff = (unsigned int)((nt * 128 + row) * INTER + ksp * 2048 + kq * 8);
    const unsigned int wBo = 8192u + CHUNK(row, kq);

    f32x4 acc[4][2];
#pragma unroll
    for (int mf = 0; mf < 4; mf++)
#pragma unroll
        for (int nf = 0; nf < 2; nf++)
#pragma unroll
            for (int v = 0; v < 4; v++) acc[mf][nf][v] = 0.f;

    int4 av; float4 b0, b1;
    av = *(const int4*)(h + aoff);
    b0 = *(const float4*)(dbase + boff); b1 = *(const float4*)(dbase + boff + 4);

    for (int kt = 0; kt < 64; kt++) {             // 2048 K per split
        const unsigned int bb = (unsigned int)(kt & 1) << 14;
        *(int4*)(lds + bb + wAo) = av;
        *(uint4*)(lds + bb + wBo) = pack8trunc(b0, b1);
        if (kt < 63) {
            const int ko = (kt + 1) * 32;
            av = *(const int4*)(h + aoff + ko);
            b0 = *(const float4*)(dbase + boff + ko); b1 = *(const float4*)(dbase + boff + ko + 4);
        }
        block_sync();
        const unsigned int kqr = (unsigned int)(lane >> 4);
        const unsigned int rl = (unsigned int)(lane & 15);
        bf16x8 a[4];
#pragma unroll
        for (int mf = 0; mf < 4; mf++)
            a[mf] = *(const bf16x8*)(lds + bb + CHUNK(wm * 64 + mf * 16 + rl, kqr));
#pragma unroll
        for (int nf = 0; nf < 2; nf++) {
            bf16x8 b = *(const bf16x8*)(lds + bb + 8192 + CHUNK(wn * 32 + nf * 16 + rl, kqr));
#pragma unroll
            for (int mf = 0; mf < 4; mf++)
                acc[mf][nf] = __builtin_amdgcn_mfma_f32_16x16x32_bf16(a[mf], b, acc[mf][nf], 0, 0, 0);
        }
    }

#pragma unroll
    for (int mf = 0; mf < 4; mf++)
#pragma unroll
        for (int v = 0; v < 4; v++) {
            int il = wm * 64 + mf * 16 + ((lane >> 4) << 2) + v;
            int i = mt * 128 + il;
            if (i < cnt) {
                float w = wts[e * T_TOK + i];
                float* yrow = y + ((size_t)ksp * 4096 + hoff + i) * HIDDEN
                                + nt * 128 + wn * 32 + (lane & 15);
#pragma unroll
                for (int nf = 0; nf < 2; nf++)
                    yrow[nf * 16] = w * acc[mf][nf][v];
            }
        }
}

// -------- K4: combine (out[t] = sum over 2 experts x 2 ksplits) --------
__global__ __launch_bounds__(256) void combine_kernel(
    const float* __restrict__ y, const int* __restrict__ offsets,
    const int* __restrict__ tsel, float* __restrict__ out) {
    const int t = blockIdx.x;
    const int d = threadIdx.x * 4;
    int p0 = tsel[t * 2], p1 = tsel[t * 2 + 1];
    size_t g0 = (size_t)(offsets[p0 >> 11] + (p0 & (T_TOK - 1)));
    size_t g1 = (size_t)(offsets[p1 >> 11] + (p1 & (T_TOK - 1)));
    float4 a0 = *(const float4*)(y + g0 * HIDDEN + d);
    float4 a1 = *(const float4*)(y + (4096 + g0) * HIDDEN + d);
    float4 b0 = *(const float4*)(y + g1 * HIDDEN + d);
    float4 b1 = *(const float4*)(y + (4096 + g1) * HIDDEN + d);
    float4 o;
    o.x = (a0.x + a1.x) + (b0.x + b1.x);
    o.y = (a0.y + a1.y) + (b0.y + b1.y);
    o.z = (a0.z + a1.z) + (b0.z + b1.z);
    o.w = (a0.w + a1.w) + (b0.w + b1.w);
    *(float4*)(out + (size_t)t * HIDDEN + d) = o;
}

extern "C" void kernel_launch(void* const* d_in, const int* in_sizes, int n_in,
                              void* d_out, int out_size, void* d_ws, size_t ws_size,
                              hipStream_t stream) {
    const float* x  = (const float*)d_in[0];
    const float* rw = (const float*)d_in[1];
    const float* gw = (const float*)d_in[2];
    const float* uw = (const float*)d_in[3];
    const float* dw = (const float*)d_in[4];
    float* out = (float*)d_out;
    float* logits = out + (size_t)T_TOK * HIDDEN;

    char* ws = (char*)d_ws;
    int*   counts  = (int*)ws;                         // 32 B
    int*   offsets = (int*)(ws + 32);                  // 32 B
    int*   tsel    = (int*)(ws + 1024);                // 16 KB
    int*   ids     = (int*)(ws + 20480);               // 64 KB
    float* wts     = (float*)(ws + 90112);             // 64 KB
    unsigned short* h = (unsigned short*)(ws + 262144);        // 33.55 MB
    float* y       = (float*)(ws + 262144 + 33554432);         // 2 x 16.78 MB

    hipMemsetAsync(counts, 0, 8 * sizeof(int), stream);

    router_kernel<<<T_TOK / 4, 256, 0, stream>>>(x, rw, logits, counts, ids, wts, tsel);
    scan_kernel<<<1, 64, 0, stream>>>(counts, offsets);
    // XCD-pinned 1D grids: e = bid & 7 (8 experts <-> 8 XCDs)
    gemm_gu<<<NEXP * 8 * (INTER / 128), 1024, 0, stream>>>(x, gw, uw, counts, offsets, ids, h);
    gemm_down<<<NEXP * 16 * (HIDDEN / 128) * 2, 512, 0, stream>>>(h, dw, counts, offsets, wts, y);
    combine_kernel<<<T_TOK, 256, 0, stream>>>(y, offsets, tsel, out);
}